// Round 1
// 767.486 us; speedup vs baseline: 1.0588x; 1.0588x over previous
//
#include <hip/hip_runtime.h>

typedef unsigned short u16;
typedef short bf16x8 __attribute__((ext_vector_type(8)));
typedef float f32x4 __attribute__((ext_vector_type(4)));

#define MFMA16(a, b, c) __builtin_amdgcn_mfma_f32_16x16x32_bf16((a), (b), (c), 0, 0, 0)

__device__ __forceinline__ u16 f2bf(float f) {
  union { float f; unsigned u; } v; v.f = f;
  unsigned r = v.u + 0x7fffu + ((v.u >> 16) & 1u);
  return (u16)(r >> 16);
}
__device__ __forceinline__ float bf2f(u16 u) {
  union { unsigned u; float f; } v; v.u = ((unsigned)u) << 16;
  return v.f;
}

// async global->LDS, 16B per lane. Dest must be linear in lane order.
__device__ __forceinline__ void load_lds16(const u16* g, u16* l) {
  __builtin_amdgcn_global_load_lds(
      (const __attribute__((address_space(1))) unsigned int*)g,
      (__attribute__((address_space(3))) unsigned int*)l, 16, 0, 0);
}

// ---------------------------------------------------------------- convert q/k/v -> bf16
__global__ __launch_bounds__(256) void convert_qkv(
    const float* __restrict__ q, const float* __restrict__ k, const float* __restrict__ v,
    u16* __restrict__ qb, u16* __restrict__ kb, u16* __restrict__ vb) {
  const int t = blockIdx.x * 256 + threadIdx.x;  // float4 index, 0..1M-1
  const float* src = (blockIdx.y == 0) ? q : (blockIdx.y == 1) ? k : v;
  u16* dst = (blockIdx.y == 0) ? qb : (blockIdx.y == 1) ? kb : vb;
  float4 f = ((const float4*)src)[t];
  ushort4 u;
  u.x = f2bf(f.x); u.y = f2bf(f.y); u.z = f2bf(f.z); u.w = f2bf(f.w);
  ((ushort4*)dst)[t] = u;
}

// ---------------------------------------------------------------- W [K][N] fp32 -> WT [N][K] bf16
__global__ __launch_bounds__(256) void transpose_w(
    const float* __restrict__ W0, const float* __restrict__ W1,
    const float* __restrict__ W2, const float* __restrict__ W3,
    u16* __restrict__ T0, u16* __restrict__ T1, u16* __restrict__ T2, u16* __restrict__ T3) {
  __shared__ float tile[64][65];
  const float* W = (blockIdx.y == 0) ? W0 : (blockIdx.y == 1) ? W1 : (blockIdx.y == 2) ? W2 : W3;
  u16* T = (blockIdx.y == 0) ? T0 : (blockIdx.y == 1) ? T1 : (blockIdx.y == 2) ? T2 : T3;
  const int bx = blockIdx.x;
  const int kt = (bx >> 4) * 64, nt = (bx & 15) * 64;
  const int t = threadIdx.x;
#pragma unroll
  for (int i = 0; i < 16; ++i) {
    int e = t + i * 256, r = e >> 6, c = e & 63;
    tile[r][c] = W[(size_t)(kt + r) * 1024 + nt + c];
  }
  __syncthreads();
#pragma unroll
  for (int i = 0; i < 16; ++i) {
    int e = t + i * 256, rn = e >> 6, ck = e & 63;
    T[(size_t)(nt + rn) * 1024 + kt + ck] = f2bf(tile[ck][rn]);
  }
}

// ---------------------------------------------------------------- GEMM core
// C = A[4096x1024] * Bt^T + bias, block tile BM x 128, BK=64, 4 waves (2x2).
// LDS is LINEAR stride-64 with XOR swizzle applied to the GLOBAL source column
// group on staging and to the ds_read address on the fragment read (rule #21).
// mode 0: dst bf16 [B,H,S,Dh]; mode 1: dst bf16 [B,H,Dh,S]; mode 2: dst fp32 row-major.
template <int BM>
__device__ __forceinline__ void gemm_core(
    const u16* __restrict__ A, const u16* __restrict__ Bt,
    const float* __restrict__ bias, void* __restrict__ dstv, const int mode) {
  constexpr int WM = BM / 2;    // wave tile M (64 or 32)
  constexpr int MI = WM / 16;   // 4 or 2
  constexpr int LA = BM / 32;   // A gload_lds per thread per K-step
  __shared__ __align__(16) u16 As[BM * 64];
  __shared__ __align__(16) u16 Bs[128 * 64];
  const int tid = threadIdx.x;
  const int wv = tid >> 6, lane = tid & 63, quad = lane >> 4, l16 = lane & 15;
  const int wq = wv >> 1, wn = wv & 1;
  const int m0 = blockIdx.y * BM, n0 = blockIdx.x * 128;

  f32x4 acc[MI][4] = {};

  for (int kt = 0; kt < 16; ++kt) {
    const int k0 = kt * 64;
    __syncthreads();
#pragma unroll
    for (int i = 0; i < LA; ++i) {
      const int e = tid + i * 256, r = e >> 3, g = e & 7;
      load_lds16(A + (size_t)(m0 + r) * 1024 + k0 + ((g ^ (r & 7)) << 3), &As[e * 8]);
    }
#pragma unroll
    for (int i = 0; i < 4; ++i) {
      const int e = tid + i * 256, r = e >> 3, g = e & 7;
      load_lds16(Bt + (size_t)(n0 + r) * 1024 + k0 + ((g ^ (r & 7)) << 3), &Bs[e * 8]);
    }
    __syncthreads();
#pragma unroll
    for (int kk = 0; kk < 2; ++kk) {
      bf16x8 af[MI], bf[4];
      const int ce = kk * 32 + quad * 8;  // element offset in row
#pragma unroll
      for (int mi = 0; mi < MI; ++mi) {
        const int row = wq * WM + mi * 16 + l16;
        af[mi] = *(const bf16x8*)(&As[row * 64 + (ce ^ ((row & 7) << 3))]);
      }
#pragma unroll
      for (int ni = 0; ni < 4; ++ni) {
        const int row = wn * 64 + ni * 16 + l16;
        bf[ni] = *(const bf16x8*)(&Bs[row * 64 + (ce ^ ((row & 7) << 3))]);
      }
#pragma unroll
      for (int mi = 0; mi < MI; ++mi)
#pragma unroll
        for (int ni = 0; ni < 4; ++ni)
          acc[mi][ni] = MFMA16(af[mi], bf[ni], acc[mi][ni]);
    }
  }
#pragma unroll
  for (int ni = 0; ni < 4; ++ni) {
    const int col = n0 + wn * 64 + ni * 16 + l16;
    const float bv = bias[col];
#pragma unroll
    for (int mi = 0; mi < MI; ++mi) {
#pragma unroll
      for (int r = 0; r < 4; ++r) {
        const int row = m0 + wq * WM + mi * 16 + quad * 4 + r;
        const float val = acc[mi][ni][r] + bv;
        if (mode == 2) {
          ((float*)dstv)[(size_t)row * 1024 + col] = val;
        } else {
          const int bb = row >> 11, s = row & 2047, h = col >> 6, dh = col & 63;
          if (mode == 0)
            ((u16*)dstv)[((size_t)((bb << 4) + h) * 2048 + s) * 64 + dh] = f2bf(val);
          else
            ((u16*)dstv)[((size_t)((bb << 4) + h) * 64 + dh) * 2048 + s] = f2bf(val);
        }
      }
    }
  }
}

// merged QKV projection: grid (8, 32, 3) -> 768 blocks, ~3 blocks/CU
__global__ __launch_bounds__(256, 2) void gemm_qkv(
    const u16* __restrict__ qb, const u16* __restrict__ kb, const u16* __restrict__ vb,
    const u16* __restrict__ WqT, const u16* __restrict__ WkT, const u16* __restrict__ WvT,
    const float* __restrict__ bq, const float* __restrict__ bk, const float* __restrict__ bv,
    u16* __restrict__ qhp, u16* __restrict__ khp, u16* __restrict__ vhT) {
  const int z = blockIdx.z;
  const u16* A = (z == 0) ? qb : (z == 1) ? kb : vb;
  const u16* Bt = (z == 0) ? WqT : (z == 1) ? WkT : WvT;
  const float* bias = (z == 0) ? bq : (z == 1) ? bk : bv;
  void* dst = (z == 0) ? (void*)qhp : (z == 1) ? (void*)khp : (void*)vhT;
  gemm_core<128>(A, Bt, bias, dst, (z == 2) ? 1 : 0);
}

// output projection: BM=64 -> grid (8, 64) = 512 blocks, 2 blocks/CU
__global__ __launch_bounds__(256, 2) void gemm_o(
    const u16* __restrict__ ctx, const u16* __restrict__ WoT,
    const float* __restrict__ bo, float* __restrict__ out) {
  gemm_core<64>(ctx, WoT, bo, (void*)out, 2);
}

// ---------------------------------------------------------------- fused attention
// One block per (b,h, 64-row q-tile). Two passes over K chunks of 128.
// Pass1: QK^T -> rowsum of exp (no max subtraction: |scores| <~ 8).
// Pass2: QK^T -> P = exp*inv_l - 1e9*mask -> LDS bf16 -> (a) fp32 att write (b) P@V MFMA.
// K/V staged via global_load_lds into linear LDS with source-side XOR swizzle.
__global__ __launch_bounds__(256, 2) void attn_fused(
    const u16* __restrict__ qh, const u16* __restrict__ kh, const u16* __restrict__ vhT,
    const float* __restrict__ maskg, float* __restrict__ attg, u16* __restrict__ ctx) {
  __shared__ __align__(16) u16 Qs[64 * 64];    // swizzled, rows 128B
  __shared__ __align__(16) u16 Ks[128 * 64];   // swizzled, rows 128B
  __shared__ __align__(16) u16 Vs[64 * 128];   // swizzled, rows 256B
  __shared__ __align__(16) u16 Ps[64 * 136];
  __shared__ float msk[128];
  __shared__ float lpart[4][64];

  const int tid = threadIdx.x;
  const int wv = tid >> 6, lane = tid & 63, quad = lane >> 4, l16 = lane & 15;
  const int bx = blockIdx.x, bh = bx >> 5, qi = bx & 31;
  const int b = bh >> 4, h = bh & 15;
  const int q0 = qi * 64;

  {  // stage Q tile once (64x64), reg-staged into swizzled layout
    const u16* qsrc = qh + ((size_t)bh * 2048 + q0) * 64;
#pragma unroll
    for (int i = 0; i < 2; ++i) {
      int e = tid + i * 256, r = e >> 3, g = e & 7;
      *(uint4*)(&Qs[r * 64 + ((g ^ (r & 7)) << 3)]) = *(const uint4*)(qsrc + r * 64 + (g << 3));
    }
  }

  // ---------------- pass 1: row sums of exp(scores/8)
  float l_acc[4][4] = {};
  for (int c = 0; c < 16; ++c) {
    __syncthreads();
    const u16* ksrc = kh + ((size_t)bh * 2048 + c * 128) * 64;
#pragma unroll
    for (int i = 0; i < 4; ++i) {
      int e = tid + i * 256, r = e >> 3, g = e & 7;
      load_lds16(ksrc + r * 64 + ((g ^ (r & 7)) << 3), &Ks[e * 8]);
    }
    __syncthreads();
    f32x4 s[4][2] = {};
#pragma unroll
    for (int kk = 0; kk < 2; ++kk) {
      bf16x8 af[4], bf[2];
      const int ce = kk * 32 + quad * 8;
#pragma unroll
      for (int mi = 0; mi < 4; ++mi) {
        const int row = mi * 16 + l16;
        af[mi] = *(const bf16x8*)(&Qs[row * 64 + (ce ^ ((row & 7) << 3))]);
      }
#pragma unroll
      for (int ni = 0; ni < 2; ++ni) {
        const int row = wv * 32 + ni * 16 + l16;
        bf[ni] = *(const bf16x8*)(&Ks[row * 64 + (ce ^ ((row & 7) << 3))]);
      }
#pragma unroll
      for (int mi = 0; mi < 4; ++mi)
#pragma unroll
        for (int ni = 0; ni < 2; ++ni)
          s[mi][ni] = MFMA16(af[mi], bf[ni], s[mi][ni]);
    }
#pragma unroll
    for (int mi = 0; mi < 4; ++mi)
#pragma unroll
      for (int r = 0; r < 4; ++r)
        l_acc[mi][r] += __expf(s[mi][0][r] * 0.125f) + __expf(s[mi][1][r] * 0.125f);
  }
  // cross-lane + cross-wave merge of row sums
#pragma unroll
  for (int mi = 0; mi < 4; ++mi)
#pragma unroll
    for (int r = 0; r < 4; ++r) {
      float v = l_acc[mi][r];
      v += __shfl_xor(v, 1); v += __shfl_xor(v, 2);
      v += __shfl_xor(v, 4); v += __shfl_xor(v, 8);
      l_acc[mi][r] = v;
    }
  if (l16 == 0) {
#pragma unroll
    for (int mi = 0; mi < 4; ++mi)
#pragma unroll
      for (int r = 0; r < 4; ++r) lpart[wv][mi * 16 + quad * 4 + r] = l_acc[mi][r];
  }
  __syncthreads();
  float inv_l[4][4];
#pragma unroll
  for (int mi = 0; mi < 4; ++mi)
#pragma unroll
    for (int r = 0; r < 4; ++r) {
      int row = mi * 16 + quad * 4 + r;
      inv_l[mi][r] = 1.0f / (lpart[0][row] + lpart[1][row] + lpart[2][row] + lpart[3][row]);
    }

  // ---------------- pass 2
  f32x4 o[4] = {};
  for (int c = 0; c < 16; ++c) {
    __syncthreads();
    {
      const u16* ksrc = kh + ((size_t)bh * 2048 + c * 128) * 64;
#pragma unroll
      for (int i = 0; i < 4; ++i) {
        int e = tid + i * 256, r = e >> 3, g = e & 7;
        load_lds16(ksrc + r * 64 + ((g ^ (r & 7)) << 3), &Ks[e * 8]);
      }
      const u16* vsrc = vhT + (size_t)bh * 64 * 2048 + c * 128;
#pragma unroll
      for (int i = 0; i < 4; ++i) {
        int e = tid + i * 256, d = e >> 4, g = e & 15;
        load_lds16(vsrc + (size_t)d * 2048 + ((g ^ (d & 15)) << 3), &Vs[e * 8]);
      }
      if (tid < 128) msk[tid] = maskg[(size_t)b * 2048 + c * 128 + tid];
    }
    __syncthreads();
    f32x4 s[4][2] = {};
#pragma unroll
    for (int kk = 0; kk < 2; ++kk) {
      bf16x8 af[4], bf[2];
      const int ce = kk * 32 + quad * 8;
#pragma unroll
      for (int mi = 0; mi < 4; ++mi) {
        const int row = mi * 16 + l16;
        af[mi] = *(const bf16x8*)(&Qs[row * 64 + (ce ^ ((row & 7) << 3))]);
      }
#pragma unroll
      for (int ni = 0; ni < 2; ++ni) {
        const int row = wv * 32 + ni * 16 + l16;
        bf[ni] = *(const bf16x8*)(&Ks[row * 64 + (ce ^ ((row & 7) << 3))]);
      }
#pragma unroll
      for (int mi = 0; mi < 4; ++mi)
#pragma unroll
        for (int ni = 0; ni < 2; ++ni)
          s[mi][ni] = MFMA16(af[mi], bf[ni], s[mi][ni]);
    }
#pragma unroll
    for (int mi = 0; mi < 4; ++mi)
#pragma unroll
      for (int ni = 0; ni < 2; ++ni) {
        const float mval = msk[wv * 32 + ni * 16 + l16];
#pragma unroll
        for (int r = 0; r < 4; ++r) {
          float p = __expf(s[mi][ni][r] * 0.125f) * inv_l[mi][r];
          Ps[(mi * 16 + quad * 4 + r) * 136 + wv * 32 + ni * 16 + l16] = f2bf(p - 1e9f * mval);
        }
      }
    __syncthreads();
    // P @ V  (A = Ps rows, B^T = Vs rows, V swizzled)
#pragma unroll
    for (int kk = 0; kk < 4; ++kk) {
      const int ce = kk * 32 + quad * 8;
      bf16x8 bfv = *(const bf16x8*)(&Vs[(wv * 16 + l16) * 128 + (ce ^ (l16 << 3))]);
#pragma unroll
      for (int mi = 0; mi < 4; ++mi) {
        bf16x8 af = *(const bf16x8*)(&Ps[(mi * 16 + l16) * 136 + kk * 32 + quad * 8]);
        o[mi] = MFMA16(af, bfv, o[mi]);
      }
    }
    // coalesced fp32 att-weight write from LDS
    float* adst = attg + ((size_t)bh * 2048 + q0) * 2048 + c * 128;
#pragma unroll
    for (int i = 0; i < 4; ++i) {
      int e = tid + i * 256, r = e >> 4, cu = (e & 15) << 3;
      uint4 pv = *(const uint4*)(&Ps[r * 136 + cu]);
      const u16* pu = (const u16*)&pv;
      float4 w0 = make_float4(bf2f(pu[0]), bf2f(pu[1]), bf2f(pu[2]), bf2f(pu[3]));
      float4 w1 = make_float4(bf2f(pu[4]), bf2f(pu[5]), bf2f(pu[6]), bf2f(pu[7]));
      *(float4*)(adst + (size_t)r * 2048 + cu) = w0;
      *(float4*)(adst + (size_t)r * 2048 + cu + 4) = w1;
    }
  }
  // ctx out, concat layout [B,S,H*Dh] bf16
#pragma unroll
  for (int mi = 0; mi < 4; ++mi)
#pragma unroll
    for (int r = 0; r < 4; ++r) {
      int row = mi * 16 + quad * 4 + r;
      ctx[((size_t)(b * 2048 + q0 + row)) * 1024 + h * 64 + wv * 16 + l16] = f2bf(o[mi][r]);
    }
}

// ----------------------------------------------------------------
extern "C" void kernel_launch(void* const* d_in, const int* in_sizes, int n_in,
                              void* d_out, int out_size, void* d_ws, size_t ws_size,
                              hipStream_t stream) {
  (void)in_sizes; (void)n_in; (void)out_size; (void)ws_size;
  const float* q = (const float*)d_in[0];
  const float* k = (const float*)d_in[1];
  const float* v = (const float*)d_in[2];
  const float* mask = (const float*)d_in[3];
  const float* Wq = (const float*)d_in[4];
  const float* bq = (const float*)d_in[5];
  const float* Wk = (const float*)d_in[6];
  const float* bk = (const float*)d_in[7];
  const float* Wv = (const float*)d_in[8];
  const float* bv = (const float*)d_in[9];
  const float* Wo = (const float*)d_in[10];
  const float* bo = (const float*)d_in[11];

  float* out = (float*)d_out;
  float* attg = out + (size_t)4194304;  // [B,H,S,S] region

  u16* ws = (u16*)d_ws;
  u16* qb = ws;                       // 4M bf16
  u16* kb = qb + (1u << 22);
  u16* vb = kb + (1u << 22);
  u16* WqT = vb + (1u << 22);         // 1M bf16 each
  u16* WkT = WqT + (1u << 20);
  u16* WvT = WkT + (1u << 20);
  u16* WoT = WvT + (1u << 20);
  u16* qhp = WoT + (1u << 20);        // 4M bf16 [B,H,S,Dh]
  u16* khp = qhp + (1u << 22);
  u16* vhT = khp + (1u << 22);        // [B,H,Dh,S]
  u16* ctx = vhT + (1u << 22);        // [B,S,D]

  convert_qkv<<<dim3(4096, 3), 256, 0, stream>>>(q, k, v, qb, kb, vb);
  transpose_w<<<dim3(256, 4), 256, 0, stream>>>(Wq, Wk, Wv, Wo, WqT, WkT, WvT, WoT);
  gemm_qkv<<<dim3(8, 32, 3), 256, 0, stream>>>(qb, kb, vb, WqT, WkT, WvT, bq, bk, bv, qhp, khp, vhT);
  attn_fused<<<dim3(1024), 256, 0, stream>>>(qhp, khp, vhT, mask, attg, ctx);
  gemm_o<<<dim3(8, 64), 256, 0, stream>>>(ctx, WoT, bo, out);
}